// Round 7
// baseline (61.994 us; speedup 1.0000x reference)
//
#include <hip/hip_runtime.h>
#include <hip/hip_bf16.h>

#define B_ 8
#define W_ 128
#define K_ 2048
#define D_ 256
#define WX 144            // padded w-dim: 128 x-cols + E1-col(128) + 15 zero cols
#define NC 256            // K/8 j-chunks
#define ROWP 68           // padded row dim in epilogue LDS array

typedef __attribute__((ext_vector_type(8))) short bf16x8;
typedef __attribute__((ext_vector_type(4))) float f32x4;

static __device__ __forceinline__ short f2bf(float f) {
    unsigned int u = __float_as_uint(f);
    unsigned int r = (u + 0x7FFFu + ((u >> 16) & 1u)) >> 16;
    return (short)r;
}

// ---------- k_pre: heterogeneous grid.
// blocks 0..511   : prep  -> u2 reduce, E1=exp(u2), xbt = bf16(x*E1) blocked (+E1 col)
// blocks 512..767 : e2    -> E2 = bf16(exp(bias-rowmax)), 8 rows/block, blocked e2t[c][i][e]
__global__ __launch_bounds__(256) void k_pre(const float* __restrict__ x,
        const float* __restrict__ W_lin, const float* __restrict__ a,
        const float* __restrict__ bias,
        short* __restrict__ xbt, short* __restrict__ e2t) {
    __shared__ float sh_red2[2][W_];
    __shared__ float sh_ws[W_];
    __shared__ float sh_red[8][33];
    __shared__ float sh_e1s[32];
    __shared__ float sh_mbs[8];
    int tid = threadIdx.x;

    if (blockIdx.x < 512) {
        // ---- prep path ----
        // inline w2v: ws[w] = sum_d W_lin[128+w][d]*a[d]
        {
            int w = tid & 127, h = tid >> 7;
            const float4* rp = (const float4*)(W_lin + (size_t)(W_ + w) * D_) + h * 32;
            const float4* ap = (const float4*)a + h * 32;
            float acc = 0.f;
#pragma unroll 8
            for (int d = 0; d < 32; ++d) {
                float4 rv = rp[d], av = ap[d];
                acc += rv.x * av.x + rv.y * av.y + rv.z * av.z + rv.w * av.w;
            }
            sh_red2[h][w] = acc;
        }
        __syncthreads();
        if (tid < W_) sh_ws[tid] = sh_red2[0][tid] + sh_red2[1][tid];
        __syncthreads();

        int q = tid & 31, cw = tid >> 5;
        int bk0 = blockIdx.x * 32;
        int b = bk0 >> 11;
        int k = (bk0 & (K_ - 1)) + q;
        const float* xp = x + ((size_t)b * W_ + cw * 16) * K_ + k;
        float xv[16];
        float acc = 0.f;
#pragma unroll
        for (int w = 0; w < 16; ++w) {
            xv[w] = xp[(size_t)w * K_];
            acc += xv[w] * sh_ws[cw * 16 + w];
        }
        sh_red[cw][q] = acc;
        __syncthreads();
        if (tid < 32) {
            float s = 0.f;
#pragma unroll
            for (int cc = 0; cc < 8; ++cc) s += sh_red[cc][tid];
            sh_e1s[tid] = __expf(s);   // |u2| small; softmax shift-invariant -> no max needed
        }
        __syncthreads();
        float e1q = sh_e1s[q];
        short* xo = xbt + (((size_t)b * NC + (k >> 3)) * WX + cw * 16) * 8 + (k & 7);
#pragma unroll
        for (int w = 0; w < 16; ++w) xo[w * 8] = f2bf(xv[w] * e1q);
        if (tid < 32) {   // E1 column (w=128)
            int kk = (bk0 & (K_ - 1)) + tid;
            xbt[(((size_t)b * NC + (kk >> 3)) * WX + 128) * 8 + (kk & 7)] = f2bf(sh_e1s[tid]);
        }
        if (tid >= 64 && tid < 124) {   // zero cols 129..143 for this block's 4 c-chunks
            int id = tid - 64;
            int cl = id / 15, wz = 129 + id % 15;
            int c = ((bk0 & (K_ - 1)) >> 3) + cl;
            bf16x8 z = {0, 0, 0, 0, 0, 0, 0, 0};
            *(bf16x8*)(xbt + (((size_t)b * NC + c) * WX + wz) * 8) = z;
        }
    } else {
        // ---- e2 path: 8 rows per block ----
        int i0 = (blockIdx.x - 512) * 8;
        {
            int r = tid >> 5, t32 = tid & 31;
            const float4* bp = (const float4*)(bias + (size_t)(i0 + r) * K_);
            float m = -1e30f;
#pragma unroll 4
            for (int s = 0; s < 16; ++s) {
                float4 v = bp[t32 + s * 32];
                m = fmaxf(m, fmaxf(fmaxf(v.x, v.y), fmaxf(v.z, v.w)));
            }
#pragma unroll
            for (int mm = 1; mm < 32; mm <<= 1) m = fmaxf(m, __shfl_xor(m, mm));
            if (t32 == 0) sh_mbs[r] = m;
        }
        __syncthreads();
        int il = tid & 7, cg = tid >> 3;    // cg 0..31
        float mb = sh_mbs[il];
        int i = i0 + il;
        const float4* brow = (const float4*)(bias + (size_t)i * K_);
#pragma unroll 2
        for (int it = 0; it < 8; ++it) {
            int c = cg * 8 + it;
            float4 v0 = brow[c * 2];
            float4 v1 = brow[c * 2 + 1];
            bf16x8 o;
            o[0] = f2bf(__expf(v0.x - mb)); o[1] = f2bf(__expf(v0.y - mb));
            o[2] = f2bf(__expf(v0.z - mb)); o[3] = f2bf(__expf(v0.w - mb));
            o[4] = f2bf(__expf(v1.x - mb)); o[5] = f2bf(__expf(v1.y - mb));
            o[6] = f2bf(__expf(v1.z - mb)); o[7] = f2bf(__expf(v1.w - mb));
            *(bf16x8*)(e2t + ((size_t)c * K_ + i) * 8) = o;
        }
    }
}

// ---------- k_attn: pure GEMM D[i,wcol] = sum_j E2[i,j]*X'[wcol,j]; col 128 = l.
// grid 256 (1D): b = blk&7 (XCD-local), i0 = (blk>>3)*64. 512 thr = 8 waves =
// 2 m-halves (mh: rows i0+mh*32..+31, two 16-row MFMA tiles) x 4 j-slices (512 j each).
// Depth-1 X/Y prefetch; launch_bounds(512,2) -> 1 block/CU, VGPR cap 256.
struct SetG {
    bf16x8 A0, A1;
    bf16x8 B0, B1, B2, B3, B4, B5, B6, B7, B8;
};

#define FETCHG(S, c_) do {                                         \
    const short* _e = eA + (size_t)(c_) * (K_ * 8);                \
    const short* _x = xB + (size_t)(c_) * (WX * 8);                \
    S.A0 = *(const bf16x8*)(_e);                                   \
    S.A1 = *(const bf16x8*)(_e + 128);                             \
    S.B0 = *(const bf16x8*)(_x);                                   \
    S.B1 = *(const bf16x8*)(_x + 128);                             \
    S.B2 = *(const bf16x8*)(_x + 256);                             \
    S.B3 = *(const bf16x8*)(_x + 384);                             \
    S.B4 = *(const bf16x8*)(_x + 512);                             \
    S.B5 = *(const bf16x8*)(_x + 640);                             \
    S.B6 = *(const bf16x8*)(_x + 768);                             \
    S.B7 = *(const bf16x8*)(_x + 896);                             \
    S.B8 = *(const bf16x8*)(_x + 1024);                            \
} while (0)

#define MF(a_, b_, c_) __builtin_amdgcn_mfma_f32_16x16x32_bf16(a_, b_, c_, 0, 0, 0)

#define CONSUMEG(S) do {                                           \
    acc0[0] = MF(S.A0, S.B0, acc0[0]); acc1[0] = MF(S.A1, S.B0, acc1[0]); \
    acc0[1] = MF(S.A0, S.B1, acc0[1]); acc1[1] = MF(S.A1, S.B1, acc1[1]); \
    acc0[2] = MF(S.A0, S.B2, acc0[2]); acc1[2] = MF(S.A1, S.B2, acc1[2]); \
    acc0[3] = MF(S.A0, S.B3, acc0[3]); acc1[3] = MF(S.A1, S.B3, acc1[3]); \
    acc0[4] = MF(S.A0, S.B4, acc0[4]); acc1[4] = MF(S.A1, S.B4, acc1[4]); \
    acc0[5] = MF(S.A0, S.B5, acc0[5]); acc1[5] = MF(S.A1, S.B5, acc1[5]); \
    acc0[6] = MF(S.A0, S.B6, acc0[6]); acc1[6] = MF(S.A1, S.B6, acc1[6]); \
    acc0[7] = MF(S.A0, S.B7, acc0[7]); acc1[7] = MF(S.A1, S.B7, acc1[7]); \
    acc0[8] = MF(S.A0, S.B8, acc0[8]); acc1[8] = MF(S.A1, S.B8, acc1[8]); \
} while (0)

__global__ __launch_bounds__(512, 2) void k_attn(const short* __restrict__ e2t,
        const short* __restrict__ xbt, float* __restrict__ out) {
    __shared__ f32x4 Rbuf[2][2][18][64];   // 73728 B; reused as [144][ROWP] f32 epilogue
    int blk  = blockIdx.x;
    int b    = blk & 7;                  // XCD round-robin -> same b per XCD
    int i0   = (blk >> 3) * 64;
    int tid  = threadIdx.x;
    int wid  = tid >> 6;
    int lane = tid & 63;
    int il   = lane & 15;
    int kg   = lane >> 4;
    int mh   = wid >> 2;                 // m-half: rows i0+mh*32 .. +31
    int js   = wid & 3;                  // j-slice: 512 j each

    const short* eA = e2t + (((size_t)(js * 64 + kg)) * K_ + i0 + mh * 32 + il) * 8;
    const short* xB = xbt + (((size_t)b * NC + js * 64 + kg) * WX + il) * 8;

    f32x4 acc0[9], acc1[9];
#pragma unroll
    for (int n = 0; n < 9; ++n) { acc0[n] = (f32x4){0,0,0,0}; acc1[n] = (f32x4){0,0,0,0}; }

    SetG X, Y;
    FETCHG(X, 0);
    for (int s = 0; s < 16; s += 2) {       // 16 k-steps of 32 j (4 c-chunks)
        FETCHG(Y, (s + 1) * 4);
        CONSUMEG(X);
        if (s + 2 < 16) FETCHG(X, (s + 2) * 4);
        CONSUMEG(Y);
    }

#define DUMPG(m_, s_) do {                                          \
    _Pragma("unroll") for (int n = 0; n < 9; ++n) {                 \
        Rbuf[m_][s_][n][lane] = acc0[n];                            \
        Rbuf[m_][s_][9 + n][lane] = acc1[n]; } } while (0)
#define GATHG(m_, s_) do {                                          \
    _Pragma("unroll") for (int n = 0; n < 9; ++n) {                 \
        acc0[n] += Rbuf[m_][s_][n][lane];                           \
        acc1[n] += Rbuf[m_][s_][9 + n][lane]; } } while (0)

    // per-mh tree reduction over 4 j-slices: 4 -> 2 -> 1
    if (js >= 2) DUMPG(mh, js - 2);
    __syncthreads();
    if (js < 2) GATHG(mh, js);
    __syncthreads();
    if (js == 1) DUMPG(mh, 0);
    __syncthreads();
    if (js == 0) GATHG(mh, 0);
    __syncthreads();                      // all reads of Rbuf done before overwrite
    if (js == 0) {
        float* arr = (float*)Rbuf;        // [col 144][ROWP rows]
#pragma unroll
        for (int n = 0; n < 9; ++n) {
            *(f32x4*)(arr + (n * 16 + il) * ROWP + mh * 32 + kg * 4)      = acc0[n];
            *(f32x4*)(arr + (n * 16 + il) * ROWP + mh * 32 + 16 + kg * 4) = acc1[n];
        }
    }
    __syncthreads();

    // epilogue: col = tid>>2 (0..127), rows rg..rg+15; l in col 128
    {
        float* arr = (float*)Rbuf;
        int col = tid >> 2;
        int rg  = (tid & 3) * 16;
        float* np = arr + col * ROWP + rg;
        float* lp = arr + 128 * ROWP + rg;
        float* op = out + ((size_t)b * W_ + col) * K_ + i0 + rg;
#pragma unroll
        for (int t = 0; t < 4; ++t) {
            f32x4 nv = *(f32x4*)(np + t * 4);
            f32x4 lv = *(f32x4*)(lp + t * 4);
            float4 o;
            o.x = 1.f / (1.f + __expf(-nv[0] / lv[0]));
            o.y = 1.f / (1.f + __expf(-nv[1] / lv[1]));
            o.z = 1.f / (1.f + __expf(-nv[2] / lv[2]));
            o.w = 1.f / (1.f + __expf(-nv[3] / lv[3]));
            *(float4*)(op + t * 4) = o;
        }
    }
}

extern "C" void kernel_launch(void* const* d_in, const int* in_sizes, int n_in,
                              void* d_out, int out_size, void* d_ws, size_t ws_size,
                              hipStream_t stream) {
    const float* x     = (const float*)d_in[0];
    const float* W_lin = (const float*)d_in[1];
    // d_in[2] = b_lin: constant along softmax axis -> cancels, unused
    const float* a     = (const float*)d_in[3];
    const float* bias  = (const float*)d_in[4];
    float* out = (float*)d_out;

    short* xbt = (short*)d_ws;                    // 8*256*144*8 bf16 = 4.72 MB
    short* e2t = xbt + (size_t)B_ * NC * WX * 8;  // 256*2048*8 bf16 = 8 MB

    k_pre <<<768, 256, 0, stream>>>(x, W_lin, a, bias, xbt, e2t);
    k_attn<<<256, 512, 0, stream>>>(e2t, xbt, out);
}

// Round 8
// 46.062 us; speedup vs baseline: 1.3459x; 1.3459x over previous
//
#include <hip/hip_runtime.h>
#include <hip/hip_bf16.h>

#define B_ 8
#define W_ 128
#define K_ 2048
#define D_ 256
#define WX 144            // padded w-dim: 128 x-cols + E1-col(128) + 15 zero cols
#define NC 256            // K/8 j-chunks

typedef __attribute__((ext_vector_type(8))) short bf16x8;
typedef __attribute__((ext_vector_type(4))) float f32x4;

static __device__ __forceinline__ short f2bf(float f) {
    unsigned int u = __float_as_uint(f);
    unsigned int r = (u + 0x7FFFu + ((u >> 16) & 1u)) >> 16;
    return (short)r;
}

// ---------- k_w2v: w2v[w] = sum_d W_lin[W+w][d] * a[d]  (128 blocks x 1 wave)
__global__ void k_w2v(const float* __restrict__ W_lin, const float* __restrict__ a,
                      float* __restrict__ w2v) {
    int w = blockIdx.x, l = threadIdx.x;
    float4 rv = ((const float4*)(W_lin + (size_t)(W_ + w) * D_))[l];
    float4 av = ((const float4*)a)[l];
    float acc = rv.x * av.x + rv.y * av.y + rv.z * av.z + rv.w * av.w;
    for (int m = 1; m < 64; m <<= 1) acc += __shfl_xor(acc, m);
    if (l == 0) w2v[w] = acc;
}

// ---------- k_pe: heterogeneous grid, w2v read from global (NOT inlined).
// blocks 0..511   : prep -> u2 reduce, E1=exp(u2), xbt = bf16(x*E1) blocked (+E1 col)
// blocks 512..767 : e2   -> E2 = bf16(exp(bias-rowmax)), 8 rows/block, e2t[c][i][e]
__global__ __launch_bounds__(256) void k_pe(const float* __restrict__ x,
        const float* __restrict__ w2v, const float* __restrict__ bias,
        short* __restrict__ xbt, short* __restrict__ e2t) {
    __shared__ float sh_ws[W_];
    __shared__ float sh_red[8][33];
    __shared__ float sh_e1s[32];
    __shared__ float sh_mbs[8];
    int tid = threadIdx.x;

    if (blockIdx.x < 512) {
        // ---- prep path ----
        if (tid < W_) sh_ws[tid] = w2v[tid];
        __syncthreads();
        int q = tid & 31, cw = tid >> 5;
        int bk0 = blockIdx.x * 32;
        int b = bk0 >> 11;
        int k = (bk0 & (K_ - 1)) + q;
        const float* xp = x + ((size_t)b * W_ + cw * 16) * K_ + k;
        float xv[16];
        float acc = 0.f;
#pragma unroll
        for (int w = 0; w < 16; ++w) {
            xv[w] = xp[(size_t)w * K_];
            acc += xv[w] * sh_ws[cw * 16 + w];
        }
        sh_red[cw][q] = acc;
        __syncthreads();
        if (tid < 32) {
            float s = 0.f;
#pragma unroll
            for (int cc = 0; cc < 8; ++cc) s += sh_red[cc][tid];
            sh_e1s[tid] = __expf(s);   // |u2| small; softmax shift-invariant -> no max shift
        }
        __syncthreads();
        float e1q = sh_e1s[q];
        short* xo = xbt + (((size_t)b * NC + (k >> 3)) * WX + cw * 16) * 8 + (k & 7);
#pragma unroll
        for (int w = 0; w < 16; ++w) xo[w * 8] = f2bf(xv[w] * e1q);
        if (tid < 32) {   // E1 column (w=128)
            int kk = (bk0 & (K_ - 1)) + tid;
            xbt[(((size_t)b * NC + (kk >> 3)) * WX + 128) * 8 + (kk & 7)] = f2bf(sh_e1s[tid]);
        }
        if (tid >= 64 && tid < 124) {   // zero cols 129..143 for this block's 4 c-chunks
            int id = tid - 64;
            int cl = id / 15, wz = 129 + id % 15;
            int c = ((bk0 & (K_ - 1)) >> 3) + cl;
            bf16x8 z = {0, 0, 0, 0, 0, 0, 0, 0};
            *(bf16x8*)(xbt + (((size_t)b * NC + c) * WX + wz) * 8) = z;
        }
    } else {
        // ---- e2 path: 8 rows per block, 256 blocks ----
        int i0 = (blockIdx.x - 512) * 8;
        {
            int r = tid >> 5, t32 = tid & 31;
            const float4* bp = (const float4*)(bias + (size_t)(i0 + r) * K_);
            float m = -1e30f;
#pragma unroll 4
            for (int s = 0; s < 16; ++s) {
                float4 v = bp[t32 + s * 32];
                m = fmaxf(m, fmaxf(fmaxf(v.x, v.y), fmaxf(v.z, v.w)));
            }
#pragma unroll
            for (int mm = 1; mm < 32; mm <<= 1) m = fmaxf(m, __shfl_xor(m, mm));
            if (t32 == 0) sh_mbs[r] = m;
        }
        __syncthreads();
        int il = tid & 7, cg = tid >> 3;    // cg 0..31
        float mb = sh_mbs[il];
        int i = i0 + il;
        const float4* brow = (const float4*)(bias + (size_t)i * K_);
#pragma unroll 2
        for (int it = 0; it < 8; ++it) {
            int c = cg * 8 + it;
            float4 v0 = brow[c * 2];
            float4 v1 = brow[c * 2 + 1];
            bf16x8 o;
            o[0] = f2bf(__expf(v0.x - mb)); o[1] = f2bf(__expf(v0.y - mb));
            o[2] = f2bf(__expf(v0.z - mb)); o[3] = f2bf(__expf(v0.w - mb));
            o[4] = f2bf(__expf(v1.x - mb)); o[5] = f2bf(__expf(v1.y - mb));
            o[6] = f2bf(__expf(v1.z - mb)); o[7] = f2bf(__expf(v1.w - mb));
            *(bf16x8*)(e2t + ((size_t)c * K_ + i) * 8) = o;
        }
    }
}

// ---------- k_attn: pure GEMM D[i,wcol] = sum_j E2[i,j]*X'[wcol,j]; col 128 = l
// EXACT round-6 structure (proven): 1D grid 512: b = blk&7 (XCD-local),
// i0 = (blk>>3)*32. 512 thr = 8 waves, wave = 2 m-tiles x 9 n x 256-j slice
// (8-way j-split). Single-buffered; launch_bounds(512,4) -> VGPR<=128,
// 2 blocks/CU = 4 waves/SIMD.
struct SetG {
    bf16x8 A0, A1;
    bf16x8 B0, B1, B2, B3, B4, B5, B6, B7, B8;
};

#define FETCHG(S, c_) do {                                         \
    const short* _e = eA + (size_t)(c_) * (K_ * 8);                \
    const short* _x = xB + (size_t)(c_) * (WX * 8);                \
    S.A0 = *(const bf16x8*)(_e);                                   \
    S.A1 = *(const bf16x8*)(_e + 128);                             \
    S.B0 = *(const bf16x8*)(_x);                                   \
    S.B1 = *(const bf16x8*)(_x + 128);                             \
    S.B2 = *(const bf16x8*)(_x + 256);                             \
    S.B3 = *(const bf16x8*)(_x + 384);                             \
    S.B4 = *(const bf16x8*)(_x + 512);                             \
    S.B5 = *(const bf16x8*)(_x + 640);                             \
    S.B6 = *(const bf16x8*)(_x + 768);                             \
    S.B7 = *(const bf16x8*)(_x + 896);                             \
    S.B8 = *(const bf16x8*)(_x + 1024);                            \
} while (0)

#define MF(a_, b_, c_) __builtin_amdgcn_mfma_f32_16x16x32_bf16(a_, b_, c_, 0, 0, 0)

#define CONSUMEG(S) do {                                           \
    acc0[0] = MF(S.A0, S.B0, acc0[0]); acc1[0] = MF(S.A1, S.B0, acc1[0]); \
    acc0[1] = MF(S.A0, S.B1, acc0[1]); acc1[1] = MF(S.A1, S.B1, acc1[1]); \
    acc0[2] = MF(S.A0, S.B2, acc0[2]); acc1[2] = MF(S.A1, S.B2, acc1[2]); \
    acc0[3] = MF(S.A0, S.B3, acc0[3]); acc1[3] = MF(S.A1, S.B3, acc1[3]); \
    acc0[4] = MF(S.A0, S.B4, acc0[4]); acc1[4] = MF(S.A1, S.B4, acc1[4]); \
    acc0[5] = MF(S.A0, S.B5, acc0[5]); acc1[5] = MF(S.A1, S.B5, acc1[5]); \
    acc0[6] = MF(S.A0, S.B6, acc0[6]); acc1[6] = MF(S.A1, S.B6, acc1[6]); \
    acc0[7] = MF(S.A0, S.B7, acc0[7]); acc1[7] = MF(S.A1, S.B7, acc1[7]); \
    acc0[8] = MF(S.A0, S.B8, acc0[8]); acc1[8] = MF(S.A1, S.B8, acc1[8]); \
} while (0)

__global__ __launch_bounds__(512, 4) void k_attn(const short* __restrict__ e2t,
        const short* __restrict__ xbt, float* __restrict__ out) {
    __shared__ f32x4 Rbuf[2][2][18][64];   // 73728 B; reused as [144][36] f32 epilogue
    int blk  = blockIdx.x;
    int b    = blk & 7;                  // XCD round-robin -> same b per XCD
    int i0   = (blk >> 3) * 32;
    int tid  = threadIdx.x;
    int wid  = tid >> 6;
    int lane = tid & 63;
    int il   = lane & 15;
    int kg   = lane >> 4;

    const short* eA = e2t + ((size_t)kg * K_ + i0 + il) * 8;
    const short* xB = xbt + (((size_t)b * NC + kg) * WX + il) * 8;

    f32x4 acc0[9], acc1[9];
#pragma unroll
    for (int n = 0; n < 9; ++n) { acc0[n] = (f32x4){0,0,0,0}; acc1[n] = (f32x4){0,0,0,0}; }

    SetG X;
    int c0 = wid * 32;                  // 32 c-chunks = 256 j per wave, 8 k-steps
    for (int s = 0; s < 8; ++s) {
        FETCHG(X, c0 + s * 4);
        CONSUMEG(X);
    }

    // 3-stage cross-wave tree reduction (8 -> 4 -> 2 -> 1)
    f32x4* R = (f32x4*)Rbuf;
#define DUMPG(slot) do {                                            \
    _Pragma("unroll") for (int n = 0; n < 9; ++n) {                 \
        R[((slot) * 18 + n) * 64 + lane] = acc0[n];                 \
        R[((slot) * 18 + 9 + n) * 64 + lane] = acc1[n]; } } while (0)
#define GATHG(slot) do {                                            \
    _Pragma("unroll") for (int n = 0; n < 9; ++n) {                 \
        acc0[n] += R[((slot) * 18 + n) * 64 + lane];                \
        acc1[n] += R[((slot) * 18 + 9 + n) * 64 + lane]; } } while (0)

    if (wid >= 4) DUMPG(wid - 4);
    __syncthreads();
    if (wid < 4) GATHG(wid);
    __syncthreads();
    if (wid == 2 || wid == 3) DUMPG(wid - 2);
    __syncthreads();
    if (wid < 2) GATHG(wid);
    __syncthreads();
    if (wid == 1) DUMPG(0);
    __syncthreads();
    if (wid == 0) {
        GATHG(0);
        float* arr = (float*)Rbuf;   // [col 144][36 padded rows] = 20.7 KB
#pragma unroll
        for (int n = 0; n < 9; ++n) {
            *(f32x4*)(arr + (n * 16 + il) * 36 + kg * 4)      = acc0[n];
            *(f32x4*)(arr + (n * 16 + il) * 36 + 16 + kg * 4) = acc1[n];
        }
    }
    __syncthreads();

    // epilogue: col = tid>>2 (0..127), rows rs..rs+7; l in col 128
    {
        float* arr = (float*)Rbuf;
        int col = tid >> 2;
        int rs  = (tid & 3) * 8;
        f32x4 n0 = *(f32x4*)(arr + col * 36 + rs);
        f32x4 n1 = *(f32x4*)(arr + col * 36 + rs + 4);
        f32x4 l0 = *(f32x4*)(arr + 128 * 36 + rs);
        f32x4 l1 = *(f32x4*)(arr + 128 * 36 + rs + 4);
        float4 o0, o1;
        o0.x = 1.f / (1.f + __expf(-n0[0] / l0[0]));
        o0.y = 1.f / (1.f + __expf(-n0[1] / l0[1]));
        o0.z = 1.f / (1.f + __expf(-n0[2] / l0[2]));
        o0.w = 1.f / (1.f + __expf(-n0[3] / l0[3]));
        o1.x = 1.f / (1.f + __expf(-n1[0] / l1[0]));
        o1.y = 1.f / (1.f + __expf(-n1[1] / l1[1]));
        o1.z = 1.f / (1.f + __expf(-n1[2] / l1[2]));
        o1.w = 1.f / (1.f + __expf(-n1[3] / l1[3]));
        float* op = out + ((size_t)b * W_ + col) * K_ + i0 + rs;
        *(float4*)op = o0;
        *(float4*)(op + 4) = o1;
    }
}

extern "C" void kernel_launch(void* const* d_in, const int* in_sizes, int n_in,
                              void* d_out, int out_size, void* d_ws, size_t ws_size,
                              hipStream_t stream) {
    const float* x     = (const float*)d_in[0];
    const float* W_lin = (const float*)d_in[1];
    // d_in[2] = b_lin: constant along softmax axis -> cancels, unused
    const float* a     = (const float*)d_in[3];
    const float* bias  = (const float*)d_in[4];
    float* out = (float*)d_out;

    float* w2v = (float*)d_ws;                    // 128 f32
    short* xbt = (short*)(w2v + 128);             // 8*256*144*8 bf16 = 4.72 MB
    short* e2t = xbt + (size_t)B_ * NC * WX * 8;  // 256*2048*8 bf16 = 8 MB

    k_w2v<<<128, 64, 0, stream>>>(W_lin, a, w2v);
    k_pe <<<768, 256, 0, stream>>>(x, w2v, bias, xbt, e2t);
    k_attn<<<512, 512, 0, stream>>>(e2t, xbt, out);
}

// Round 10
// 43.037 us; speedup vs baseline: 1.4405x; 1.0703x over previous
//
#include <hip/hip_runtime.h>
#include <hip/hip_bf16.h>
#include <hip/hip_cooperative_groups.h>

namespace cg = cooperative_groups;

#define B_ 8
#define W_ 128
#define K_ 2048
#define D_ 256
#define WX 144            // padded w-dim: 128 x-cols + E1-col(128) + 15 zero cols
#define NC 256            // K/8 j-chunks

typedef __attribute__((ext_vector_type(8))) short bf16x8;
typedef __attribute__((ext_vector_type(4))) float f32x4;

static __device__ __forceinline__ short f2bf(float f) {
    unsigned int u = __float_as_uint(f);
    unsigned int r = (u + 0x7FFFu + ((u >> 16) & 1u)) >> 16;
    return (short)r;
}

// ================= shared phase bodies (used by coop kernel AND fallback) ==========

// prep: block `blk` (0..511) owns 32 k-cols. 512 threads. sc = >=696 floats LDS.
static __device__ __forceinline__ void prep_body(const float* __restrict__ x,
        const float* __restrict__ w2v, short* __restrict__ xbt,
        float* sc, int blk, int tid) {
    if (tid < W_) sc[tid] = w2v[tid];          // ws
    __syncthreads();
    int q = tid & 31, cw = tid >> 5;           // cw 0..15, 8 w each
    int bk0 = blk * 32;
    int b = bk0 >> 11;
    int k = (bk0 & (K_ - 1)) + q;
    const float* xp = x + ((size_t)b * W_ + cw * 8) * K_ + k;
    float xv[8];
    float acc = 0.f;
#pragma unroll
    for (int w = 0; w < 8; ++w) {
        xv[w] = xp[(size_t)w * K_];
        acc += xv[w] * sc[cw * 8 + w];
    }
    sc[128 + cw * 33 + q] = acc;               // red[16][33]
    __syncthreads();
    if (tid < 32) {
        float s = 0.f;
#pragma unroll
        for (int cc = 0; cc < 16; ++cc) s += sc[128 + cc * 33 + tid];
        sc[656 + tid] = __expf(s);             // e1s; |u2| small, softmax shift-invariant
    }
    __syncthreads();
    float e1q = sc[656 + q];
    short* xo = xbt + (((size_t)b * NC + (k >> 3)) * WX + cw * 8) * 8 + (k & 7);
#pragma unroll
    for (int w = 0; w < 8; ++w) xo[w * 8] = f2bf(xv[w] * e1q);
    if (tid < 32) {   // E1 column (w=128)
        int kk = (bk0 & (K_ - 1)) + tid;
        xbt[(((size_t)b * NC + (kk >> 3)) * WX + 128) * 8 + (kk & 7)] = f2bf(sc[656 + tid]);
    }
    if (tid >= 64 && tid < 124) {   // zero cols 129..143, this block's 4 c-chunks
        int id = tid - 64;
        int cl = id / 15, wz = 129 + id % 15;
        int c = ((bk0 & (K_ - 1)) >> 3) + cl;
        bf16x8 z = {0, 0, 0, 0, 0, 0, 0, 0};
        *(bf16x8*)(xbt + (((size_t)b * NC + c) * WX + wz) * 8) = z;
    }
}

// e2: block `eblk` (0..511) owns 4 bias rows. 512 threads. scm2 = >=8 floats LDS.
static __device__ __forceinline__ void e2_body(const float* __restrict__ bias,
        short* __restrict__ e2t, float* scm2, int eblk, int tid, int wid, int lane) {
    int i0e = eblk * 4;
    {
        int r = tid >> 7, t128 = tid & 127;    // 4 rows x 128 thr (2 waves/row)
        const float4* bp = (const float4*)(bias + (size_t)(i0e + r) * K_);
        float m = -1e30f;
#pragma unroll
        for (int s = 0; s < 4; ++s) {
            float4 v = bp[t128 + s * 128];
            m = fmaxf(m, fmaxf(fmaxf(v.x, v.y), fmaxf(v.z, v.w)));
        }
#pragma unroll
        for (int mm = 1; mm < 64; mm <<= 1) m = fmaxf(m, __shfl_xor(m, mm));
        if (lane == 0) scm2[wid] = m;          // 8 per-wave maxes
    }
    __syncthreads();
    {
        int il = tid & 3, cg_ = tid >> 2;       // cg_ 0..127, 2 c-chunks each
        float mb = fmaxf(scm2[il * 2], scm2[il * 2 + 1]);
        int i = i0e + il;
        const float4* brow = (const float4*)(bias + (size_t)i * K_);
#pragma unroll
        for (int it = 0; it < 2; ++it) {
            int c = cg_ * 2 + it;
            float4 v0 = brow[c * 2];
            float4 v1 = brow[c * 2 + 1];
            bf16x8 o;
            o[0] = f2bf(__expf(v0.x - mb)); o[1] = f2bf(__expf(v0.y - mb));
            o[2] = f2bf(__expf(v0.z - mb)); o[3] = f2bf(__expf(v0.w - mb));
            o[4] = f2bf(__expf(v1.x - mb)); o[5] = f2bf(__expf(v1.y - mb));
            o[6] = f2bf(__expf(v1.z - mb)); o[7] = f2bf(__expf(v1.w - mb));
            *(bf16x8*)(e2t + ((size_t)c * K_ + i) * 8) = o;
        }
    }
}

// GEMM + sigmoid (r8 k_attn body, proven). Rbuf = 72KB LDS. blk 0..511, 512 thr.
struct SetG {
    bf16x8 A0, A1;
    bf16x8 B0, B1, B2, B3, B4, B5, B6, B7, B8;
};

#define FETCHG(S, c_) do {                                         \
    const short* _e = eA + (size_t)(c_) * (K_ * 8);                \
    const short* _x = xB + (size_t)(c_) * (WX * 8);                \
    S.A0 = *(const bf16x8*)(_e);                                   \
    S.A1 = *(const bf16x8*)(_e + 128);                             \
    S.B0 = *(const bf16x8*)(_x);                                   \
    S.B1 = *(const bf16x8*)(_x + 128);                             \
    S.B2 = *(const bf16x8*)(_x + 256);                             \
    S.B3 = *(const bf16x8*)(_x + 384);                             \
    S.B4 = *(const bf16x8*)(_x + 512);                             \
    S.B5 = *(const bf16x8*)(_x + 640);                             \
    S.B6 = *(const bf16x8*)(_x + 768);                             \
    S.B7 = *(const bf16x8*)(_x + 896);                             \
    S.B8 = *(const bf16x8*)(_x + 1024);                            \
} while (0)

#define MF(a_, b_, c_) __builtin_amdgcn_mfma_f32_16x16x32_bf16(a_, b_, c_, 0, 0, 0)

#define CONSUMEG(S) do {                                           \
    acc0[0] = MF(S.A0, S.B0, acc0[0]); acc1[0] = MF(S.A1, S.B0, acc1[0]); \
    acc0[1] = MF(S.A0, S.B1, acc0[1]); acc1[1] = MF(S.A1, S.B1, acc1[1]); \
    acc0[2] = MF(S.A0, S.B2, acc0[2]); acc1[2] = MF(S.A1, S.B2, acc1[2]); \
    acc0[3] = MF(S.A0, S.B3, acc0[3]); acc1[3] = MF(S.A1, S.B3, acc1[3]); \
    acc0[4] = MF(S.A0, S.B4, acc0[4]); acc1[4] = MF(S.A1, S.B4, acc1[4]); \
    acc0[5] = MF(S.A0, S.B5, acc0[5]); acc1[5] = MF(S.A1, S.B5, acc1[5]); \
    acc0[6] = MF(S.A0, S.B6, acc0[6]); acc1[6] = MF(S.A1, S.B6, acc1[6]); \
    acc0[7] = MF(S.A0, S.B7, acc0[7]); acc1[7] = MF(S.A1, S.B7, acc1[7]); \
    acc0[8] = MF(S.A0, S.B8, acc0[8]); acc1[8] = MF(S.A1, S.B8, acc1[8]); \
} while (0)

static __device__ __forceinline__ void gemm_body(const short* __restrict__ e2t,
        const short* __restrict__ xbt, float* __restrict__ out,
        f32x4* Rbuf, int blk, int tid, int wid, int lane) {
    int b    = blk & 7;                  // XCD round-robin -> same b per XCD
    int i0   = (blk >> 3) * 32;
    int il   = lane & 15;
    int kg   = lane >> 4;

    const short* eA = e2t + ((size_t)kg * K_ + i0 + il) * 8;
    const short* xB = xbt + (((size_t)b * NC + kg) * WX + il) * 8;

    f32x4 acc0[9], acc1[9];
#pragma unroll
    for (int n = 0; n < 9; ++n) { acc0[n] = (f32x4){0,0,0,0}; acc1[n] = (f32x4){0,0,0,0}; }

    SetG X;
    int c0 = wid * 32;                  // 32 c-chunks = 256 j per wave, 8 k-steps
    for (int s = 0; s < 8; ++s) {
        FETCHG(X, c0 + s * 4);
        CONSUMEG(X);
    }

    f32x4* R = Rbuf;
#define DUMPG(slot) do {                                            \
    _Pragma("unroll") for (int n = 0; n < 9; ++n) {                 \
        R[((slot) * 18 + n) * 64 + lane] = acc0[n];                 \
        R[((slot) * 18 + 9 + n) * 64 + lane] = acc1[n]; } } while (0)
#define GATHG(slot) do {                                            \
    _Pragma("unroll") for (int n = 0; n < 9; ++n) {                 \
        acc0[n] += R[((slot) * 18 + n) * 64 + lane];                \
        acc1[n] += R[((slot) * 18 + 9 + n) * 64 + lane]; } } while (0)

    __syncthreads();
    if (wid >= 4) DUMPG(wid - 4);
    __syncthreads();
    if (wid < 4) GATHG(wid);
    __syncthreads();
    if (wid == 2 || wid == 3) DUMPG(wid - 2);
    __syncthreads();
    if (wid < 2) GATHG(wid);
    __syncthreads();
    if (wid == 1) DUMPG(0);
    __syncthreads();
    if (wid == 0) {
        GATHG(0);
        float* arr = (float*)Rbuf;   // [col 144][36 padded rows]
#pragma unroll
        for (int n = 0; n < 9; ++n) {
            *(f32x4*)(arr + (n * 16 + il) * 36 + kg * 4)      = acc0[n];
            *(f32x4*)(arr + (n * 16 + il) * 36 + 16 + kg * 4) = acc1[n];
        }
    }
    __syncthreads();

    float* arr = (float*)Rbuf;
    int col = tid >> 2;
    int rs  = (tid & 3) * 8;
    f32x4 n0 = *(f32x4*)(arr + col * 36 + rs);
    f32x4 n1 = *(f32x4*)(arr + col * 36 + rs + 4);
    f32x4 l0 = *(f32x4*)(arr + 128 * 36 + rs);
    f32x4 l1 = *(f32x4*)(arr + 128 * 36 + rs + 4);
    float4 o0, o1;
    o0.x = 1.f / (1.f + __expf(-n0[0] / l0[0]));
    o0.y = 1.f / (1.f + __expf(-n0[1] / l0[1]));
    o0.z = 1.f / (1.f + __expf(-n0[2] / l0[2]));
    o0.w = 1.f / (1.f + __expf(-n0[3] / l0[3]));
    o1.x = 1.f / (1.f + __expf(-n1[0] / l1[0]));
    o1.y = 1.f / (1.f + __expf(-n1[1] / l1[1]));
    o1.z = 1.f / (1.f + __expf(-n1[2] / l1[2]));
    o1.w = 1.f / (1.f + __expf(-n1[3] / l1[3]));
    float* op = out + ((size_t)b * W_ + col) * K_ + i0 + rs;
    *(float4*)op = o0;
    *(float4*)(op + 4) = o1;
}

// ================= cooperative fused kernel =================
__global__ __launch_bounds__(512, 4) void k_all(
        const float* __restrict__ x, const float* __restrict__ W_lin,
        const float* __restrict__ a, const float* __restrict__ bias,
        short* __restrict__ xbt, short* __restrict__ e2t,
        float* __restrict__ w2v, float* __restrict__ out) {
    __shared__ f32x4 Rbuf[4][18][64];   // 72 KB; aliased as phase-1 scratch
    float* sc = (float*)Rbuf;
    int blk = blockIdx.x;
    int tid = threadIdx.x;
    int wid = tid >> 6;
    int lane = tid & 63;

    cg::grid_group grid = cg::this_grid();

    // phase 0: w2v on blocks 0..15 (8 w per block, one wave each)
    if (blk < 16) {
        int w = blk * 8 + wid;
        float4 rv = ((const float4*)(W_lin + (size_t)(W_ + w) * D_))[lane];
        float4 av = ((const float4*)a)[lane];
        float acc = rv.x * av.x + rv.y * av.y + rv.z * av.z + rv.w * av.w;
        for (int m = 1; m < 64; m <<= 1) acc += __shfl_xor(acc, m);
        if (lane == 0) w2v[w] = acc;
    }
    __threadfence();
    grid.sync();

    // phase 1: prep (32 k-cols) + e2 (4 bias rows), every block
    prep_body(x, w2v, xbt, sc, blk, tid);
    e2_body(bias, e2t, sc + 688, blk, tid, wid, lane);
    __threadfence();
    grid.sync();

    // phase 2: GEMM + sigmoid
    gemm_body(e2t, xbt, out, (f32x4*)Rbuf, blk, tid, wid, lane);
}

// ================= fallback kernels (r8 pipeline, shared bodies) =================
__global__ void k_w2v(const float* __restrict__ W_lin, const float* __restrict__ a,
                      float* __restrict__ w2v) {
    int w = blockIdx.x, l = threadIdx.x;
    float4 rv = ((const float4*)(W_lin + (size_t)(W_ + w) * D_))[l];
    float4 av = ((const float4*)a)[l];
    float acc = rv.x * av.x + rv.y * av.y + rv.z * av.z + rv.w * av.w;
    for (int m = 1; m < 64; m <<= 1) acc += __shfl_xor(acc, m);
    if (l == 0) w2v[w] = acc;
}

__global__ __launch_bounds__(512) void k_pe2(const float* __restrict__ x,
        const float* __restrict__ w2v, const float* __restrict__ bias,
        short* __restrict__ xbt, short* __restrict__ e2t) {
    __shared__ float sc[696];
    int tid = threadIdx.x, wid = tid >> 6, lane = tid & 63;
    if (blockIdx.x < 512) {
        prep_body(x, w2v, xbt, sc, blockIdx.x, tid);
    } else {
        e2_body(bias, e2t, sc + 688, blockIdx.x - 512, tid, wid, lane);
    }
}

__global__ __launch_bounds__(512, 4) void k_gemm(const short* __restrict__ e2t,
        const short* __restrict__ xbt, float* __restrict__ out) {
    __shared__ f32x4 Rbuf[4][18][64];
    int tid = threadIdx.x;
    gemm_body(e2t, xbt, out, (f32x4*)Rbuf, blockIdx.x, tid, tid >> 6, tid & 63);
}

extern "C" void kernel_launch(void* const* d_in, const int* in_sizes, int n_in,
                              void* d_out, int out_size, void* d_ws, size_t ws_size,
                              hipStream_t stream) {
    const float* x     = (const float*)d_in[0];
    const float* W_lin = (const float*)d_in[1];
    // d_in[2] = b_lin: constant along softmax axis -> cancels, unused
    const float* a     = (const float*)d_in[3];
    const float* bias  = (const float*)d_in[4];
    float* out = (float*)d_out;

    float* w2v = (float*)d_ws;                    // 128 f32
    short* xbt = (short*)(w2v + 128);             // 8*256*144*8 bf16 = 4.72 MB
    short* e2t = xbt + (size_t)B_ * NC * WX * 8;  // 256*2048*8 bf16 = 8 MB

    // capture-safe host queries: decide coop vs fallback deterministically
    int dev = 0;
    (void)hipGetDevice(&dev);
    int coopAttr = 0;
    (void)hipDeviceGetAttribute(&coopAttr, hipDeviceAttributeCooperativeLaunch, dev);
    int occ = 0;
    (void)hipOccupancyMaxActiveBlocksPerMultiprocessor(&occ, (const void*)k_all, 512, 0);

    bool done = false;
    if (coopAttr && occ >= 2) {
        void* args[] = {(void*)&x, (void*)&W_lin, (void*)&a, (void*)&bias,
                        (void*)&xbt, (void*)&e2t, (void*)&w2v, (void*)&out};
        hipError_t e = hipLaunchCooperativeKernel((void*)k_all, dim3(512), dim3(512),
                                                  args, 0, stream);
        done = (e == hipSuccess);
    }
    if (!done) {
        k_w2v<<<128, 64, 0, stream>>>(W_lin, a, w2v);
        k_pe2<<<1024, 512, 0, stream>>>(x, w2v, bias, xbt, e2t);
        k_gemm<<<512, 512, 0, stream>>>(e2t, xbt, out);
    }
}